// Round 5
// baseline (223.023 us; speedup 1.0000x reference)
//
#include <hip/hip_runtime.h>
#include <hip/hip_bf16.h>

#define NH 64

typedef float v2f __attribute__((ext_vector_type(2)));

__device__ __forceinline__ float fast_tanh(float x) {
  float ax = fabsf(x);
  float e  = __expf(-2.0f * ax);
  float y  = (1.0f - e) * __builtin_amdgcn_rcpf(1.0f + e);
  return copysignf(y, x);
}

// Monomials of layer-1 weights, padded to 12 floats/row, PAIRED for packed math:
// pairs (m0,m1)=(1,a) (m2,m3)=(b,-2a^2) (m4,m5)=(-2ab,-2b^2) (m6,m7)=(a^3,a^2b)
// (m8,m9)=(ab^2,b^3).  The -2 factors fold tanh'' = -2*y*f1 into the table.
__global__ void prep_mono(const float* __restrict__ W1, float* __restrict__ Wm) {
  int h = threadIdx.x;
  if (h >= NH) return;
  float a = W1[h];
  float b = W1[NH + h];
  float* m = Wm + h * 12;
  m[0] = 1.0f;          m[1] = a;
  m[2] = b;             m[3] = -2.0f * a * a;
  m[4] = -2.0f * a * b; m[5] = -2.0f * b * b;
  m[6] = a * a * a;     m[7] = a * a * b;
  m[8] = a * b * b;     m[9] = b * b * b;
  m[10] = 0.0f; m[11] = 0.0f;
}

// Block = 256 threads = 4 waves, 64 points/block.
// wave w owns j-range [16w,16w+16) in 4 blocks of 4; lane l owns point blockIdx*64+l.
// Jet kinds packed in pairs -> v_pk_fma_f32 (2 FLOP/slot).
// amdgpu_waves_per_eu(4,4): PIN occupancy so the allocator takes the full
// 128-VGPR budget instead of targeting 8 waves/EU and spilling to scratch
// (R4 post-mortem: 239 MB scratch WRITE_SIZE at VGPR_Count=64).
__global__ __launch_bounds__(256)
__attribute__((amdgpu_waves_per_eu(4, 4)))
void pinn_kernel(
    const float* __restrict__ phi, const float* __restrict__ theta,
    const float* __restrict__ radius, const float* __restrict__ hth,
    const float* __restrict__ hph, const float* __restrict__ br,
    const float* __restrict__ W1, const float* __restrict__ b1,
    const float* __restrict__ W2, const float* __restrict__ b2,
    const float* __restrict__ W3, const float* __restrict__ Wm,
    float* __restrict__ out, int n) {
  __shared__ float ylds[NH * 64];      // y[h][point]   16 KB
  __shared__ float red[9 * 4 * 64];    // partial T-derivs [kind][wave][point]  9 KB

  const int tid  = threadIdx.x;
  const int lane = tid & 63;
  const int wave = __builtin_amdgcn_readfirstlane(tid >> 6);
  const int pi   = blockIdx.x * 64 + lane;

  float p = 0.0f, t = 0.0f;
  if (pi < n) { p = phi[pi]; t = theta[pi]; }

  // ---- phase 1: layer-1 activations, wave w computes h in [16w,16w+16) ----
  for (int k = 0; k < 16; ++k) {
    int h = wave * 16 + k;            // wave-uniform
    float z = fmaf(p, W1[h], fmaf(t, W1[NH + h], b1[h]));
    ylds[h * 64 + lane] = fast_tanh(z);
  }
  __syncthreads();

  // ---- phase 2: jet through layer 2 for this wave's 16 j's ----
  const int jbase = wave * 16;
  float T_p = 0.f, T_t = 0.f, T_pp = 0.f, T_pt = 0.f, T_tt = 0.f;
  float T_ppp = 0.f, T_ppt = 0.f, T_ptt = 0.f, T_ttt = 0.f;

  for (int jb = 0; jb < 4; ++jb) {
    const int j0 = jbase + jb * 4;    // wave-uniform
    // acc[k][jj]: kind-pair k of j=j0+jj.
    // pairs: 0:(val,p) 1:(t,pp) 2:(pt,tt) 3:(ppp,ppt) 4:(ptt,ttt)
    v2f acc0[4], acc1[4], acc2[4], acc3[4], acc4[4];
#pragma unroll
    for (int jj = 0; jj < 4; ++jj) {
      acc0[jj] = (v2f){b2[j0 + jj], 0.f};
      acc1[jj] = (v2f){0.f, 0.f};
      acc2[jj] = (v2f){0.f, 0.f};
      acc3[jj] = (v2f){0.f, 0.f};
      acc4[jj] = (v2f){0.f, 0.f};
    }
    for (int h = 0; h < NH; ++h) {
      float yv = ylds[h * 64 + lane];
      float f1  = fmaf(-yv, yv, 1.0f);          // tanh'
      float f2a = yv * f1;                      // -tanh''/2 (mono pre-scaled)
      float f3  = f1 * fmaf(-6.0f, f1, 4.0f);   // tanh'''
      const v2f* mp = (const v2f*)(Wm + h * 12); // wave-uniform -> s_load pairs
      v2f F0 = (v2f){yv,  f1};
      v2f F1 = (v2f){f1,  f2a};
      v2f F2 = (v2f){f2a, f2a};
      v2f F3 = (v2f){f3,  f3};
      v2f P0 = F0 * mp[0];
      v2f P1 = F1 * mp[1];
      v2f P2 = F2 * mp[2];
      v2f P3 = F3 * mp[3];
      v2f P4 = F3 * mp[4];
      const float* w2r = W2 + h * NH + j0;      // wave-uniform -> s_load x4
#pragma unroll
      for (int jj = 0; jj < 4; ++jj) {
        float w = w2r[jj];
        v2f wv = (v2f){w, w};
        acc0[jj] = __builtin_elementwise_fma(wv, P0, acc0[jj]);
        acc1[jj] = __builtin_elementwise_fma(wv, P1, acc1[jj]);
        acc2[jj] = __builtin_elementwise_fma(wv, P2, acc2[jj]);
        acc3[jj] = __builtin_elementwise_fma(wv, P3, acc3[jj]);
        acc4[jj] = __builtin_elementwise_fma(wv, P4, acc4[jj]);
      }
    }
    // layer-2 tanh jet (Faa di Bruno, order 3) + W3 contraction
#pragma unroll
    for (int jj = 0; jj < 4; ++jj) {
      float z0   = acc0[jj].x, gp  = acc0[jj].y;
      float gt   = acc1[jj].x, gpp = acc1[jj].y;
      float gpt  = acc2[jj].x, gtt = acc2[jj].y;
      float zppp = acc3[jj].x, zppt = acc3[jj].y;
      float zptt = acc4[jj].x, zttt = acc4[jj].y;
      float y2 = fast_tanh(z0);
      float g1 = fmaf(-y2, y2, 1.0f);
      float g2 = -2.0f * (y2 * g1);
      float g3 = g1 * fmaf(-6.0f, g1, 4.0f);
      float gp2 = gp * gp, gt2 = gt * gt;
      float w3 = W3[j0 + jj];
      T_p  = fmaf(w3, g1 * gp, T_p);
      T_t  = fmaf(w3, g1 * gt, T_t);
      T_pp = fmaf(w3, fmaf(g2, gp2, g1 * gpp), T_pp);
      T_pt = fmaf(w3, fmaf(g2, gp * gt, g1 * gpt), T_pt);
      T_tt = fmaf(w3, fmaf(g2, gt2, g1 * gtt), T_tt);
      T_ppp = fmaf(w3, fmaf(g3, gp2 * gp, fmaf(3.0f * g2, gp * gpp, g1 * zppp)), T_ppp);
      T_ppt = fmaf(w3, fmaf(g3, gp2 * gt, fmaf(g2, fmaf(2.0f, gp * gpt, gt * gpp), g1 * zppt)), T_ppt);
      T_ptt = fmaf(w3, fmaf(g3, gp * gt2, fmaf(g2, fmaf(2.0f, gt * gpt, gp * gtt), g1 * zptt)), T_ptt);
      T_ttt = fmaf(w3, fmaf(g3, gt2 * gt, fmaf(3.0f * g2, gt * gtt, g1 * zttt)), T_ttt);
    }
  }

  // ---- reduce partials across the 4 waves ----
  red[(0 * 4 + wave) * 64 + lane] = T_p;
  red[(1 * 4 + wave) * 64 + lane] = T_t;
  red[(2 * 4 + wave) * 64 + lane] = T_pp;
  red[(3 * 4 + wave) * 64 + lane] = T_pt;
  red[(4 * 4 + wave) * 64 + lane] = T_tt;
  red[(5 * 4 + wave) * 64 + lane] = T_ppp;
  red[(6 * 4 + wave) * 64 + lane] = T_ppt;
  red[(7 * 4 + wave) * 64 + lane] = T_ptt;
  red[(8 * 4 + wave) * 64 + lane] = T_ttt;
  __syncthreads();

  if (wave == 0 && pi < n) {
    float Tq[9];
#pragma unroll
    for (int k = 0; k < 9; ++k) {
      const float* r = red + k * 256 + lane;
      Tq[k] = (r[0] + r[64]) + (r[128] + r[192]);
    }
    float Tp = Tq[0], Tt = Tq[1], Tpp = Tq[2], Tpt = Tq[3], Ttt = Tq[4];
    float Tppp = Tq[5], Tppt = Tq[6], Tptt = Tq[7], Tttt = Tq[8];

    float s = sinf(t), c = cosf(t);
    float inv_s = 1.0f / s;
    float inv_s2 = inv_s * inv_s;

    float A = Tp * inv_s + Tt;          // u_theta
    float D = Tp * inv_s - Tt;          // u_phi
    float q1 = Tpt * inv_s - Tp * c * inv_s2;               // dt(T_p/s)
    float A_t = q1 + Ttt;
    float D_t = q1 - Ttt;
    float q2 = Tptt * inv_s - 2.0f * Tpt * c * inv_s2
             + Tp * (s * s + 2.0f * c * c) * inv_s2 * inv_s; // dtt(T_p/s)
    float A_tt = q2 + Tttt;
    float D_tt = q2 - Tttt;
    float A_pp = Tppp * inv_s + Tppt;
    float D_p  = Tpp * inv_s - Tpt;
    float D_pp = Tppp * inv_s - Tppt;

    float utt   = -(A_t * s + A * c);
    float uttt  = -(A_tt * s + 2.0f * A_t * c - A * s) * s + utt * c;
    float utpp  = -A_pp;
    float upht  = D_t * s + D * c;
    float uphtt = (D_tt * s + 2.0f * D_t * c - D * s) * s + upht * c;
    float upp   = D_p;
    float uppp  = D_pp;

    float r = radius[pi];
    float inv_r = 1.0f / r;
    float inv_r2 = inv_r * inv_r;
    float div_uh = (utt + upp) * inv_r * inv_s;
    float lap_t = s * inv_r2 * uttt + utpp * inv_s2 * inv_r2;
    float lap_p = s * inv_r2 * uphtt + uppp * inv_s2 * inv_r2;
    float comp = s * (lap_t * lap_t + lap_p * lap_p);
    float sv = -(A * hth[pi] + D * hph[pi]) - br[pi] * div_uh;
    float tg = div_uh - A * (s / c) * inv_r;

    out[pi]         = A;
    out[n + pi]     = D;
    out[2 * n + pi] = div_uh;
    out[3 * n + pi] = sv;
    out[4 * n + pi] = tg;
    out[5 * n + pi] = comp;
  }
}

extern "C" void kernel_launch(void* const* d_in, const int* in_sizes, int n_in,
                              void* d_out, int out_size, void* d_ws, size_t ws_size,
                              hipStream_t stream) {
  const float* phi    = (const float*)d_in[0];
  const float* theta  = (const float*)d_in[1];
  const float* radius = (const float*)d_in[2];
  const float* hth    = (const float*)d_in[3];
  const float* hph    = (const float*)d_in[4];
  const float* br     = (const float*)d_in[5];
  const float* W1     = (const float*)d_in[6];
  const float* b1     = (const float*)d_in[7];
  const float* W2     = (const float*)d_in[8];
  const float* b2     = (const float*)d_in[9];
  const float* W3     = (const float*)d_in[10];
  (void)ws_size; (void)n_in; (void)out_size;

  float* Wm  = (float*)d_ws;           // 64*12 floats = 3 KB
  float* out = (float*)d_out;
  int n = in_sizes[0];

  prep_mono<<<1, 64, 0, stream>>>(W1, Wm);
  int nblocks = (n + 63) / 64;
  pinn_kernel<<<nblocks, 256, 0, stream>>>(
      phi, theta, radius, hth, hph, br, W1, b1, W2, b2, W3, Wm, out, n);
}

// Round 6
// 123.827 us; speedup vs baseline: 1.8011x; 1.8011x over previous
//
#include <hip/hip_runtime.h>
#include <hip/hip_bf16.h>

#define NH 64

typedef _Float16 half8 __attribute__((ext_vector_type(8)));
typedef float float4v __attribute__((ext_vector_type(4)));

__device__ __forceinline__ float fast_tanh(float x) {
  float ax = fabsf(x);
  float e  = __expf(-2.0f * ax);
  float y  = (1.0f - e) * __builtin_amdgcn_rcpf(1.0f + e);
  return copysignf(y, x);
}

// B_k[h][j] = mono_k(h) * W2[h][j], packed in MFMA B-fragment lane order for
// v_mfma_f32_16x16x32_f16:  B[k_in=quad*8+jj + 32*ks][n=col],  lane=quad*16+col.
// Slot layout (half units): frag(slot,nt,ks) at ((slot*4+nt)*2+ks)*512 + lane*8 + jj.
// Slots 0..9 = hi parts of the 10 kinds; slots 10..12 = lo parts of kinds 0..2.
// Kinds: 0:z0(y)  1:zp(f1*a) 2:zt(f1*b) 3:zpp(f2*a^2) 4:zpt(f2*ab) 5:ztt(f2*b^2)
//        6:zppp(f3*a^3) 7:zppt(f3*a^2b) 8:zptt(f3*ab^2) 9:zttt(f3*b^3)
// The -2 of tanh'' is folded into kinds 3..5 (A-side supplies f2a = y*f1).
__global__ void prep_B(const float* __restrict__ W1, const float* __restrict__ W2,
                       _Float16* __restrict__ ws) {
  int idx = blockIdx.x * 256 + threadIdx.x;
  if (idx >= NH * NH) return;
  int h = idx >> 6, j = idx & 63;
  float a = W1[h], b = W1[NH + h];
  float w2 = W2[h * NH + j];
  float mono[10] = {1.0f, a, b, -2.0f * a * a, -2.0f * a * b, -2.0f * b * b,
                    a * a * a, a * a * b, a * b * b, b * b * b};
  int ks = h >> 5, quad = (h >> 3) & 3, jj = h & 7;
  int nt = j >> 4, col = j & 15;
  int lane = quad * 16 + col;
#pragma unroll
  for (int s = 0; s < 10; ++s) {
    float v = mono[s] * w2;
    _Float16 hi = (_Float16)v;
    ws[((s * 4 + nt) * 2 + ks) * 512 + lane * 8 + jj] = hi;
    if (s < 3) {
      _Float16 lo = (_Float16)(v - (float)hi);
      ws[(((10 + s) * 4 + nt) * 2 + ks) * 512 + lane * 8 + jj] = lo;
    }
  }
}

__device__ __forceinline__ half8 ldB(const _Float16* ws, int slot, int nt, int ks, int lane) {
  return *(const half8*)(ws + ((slot * 4 + nt) * 2 + ks) * 512 + lane * 8);
}

// 256 threads = 4 waves; wave w handles point-tile blockIdx*4+w (16 points).
// MFMA 16x16x32 f16: M=16 points, N=64 j (4 ntiles), K=64 h (2 ksteps).
// hi/lo f16 split (3 MFMAs) on kinds 0..2; hi-only on kinds 3..9.
__global__ __launch_bounds__(256) __attribute__((amdgpu_waves_per_eu(2, 2)))
void pinn_mfma(
    const float* __restrict__ phi, const float* __restrict__ theta,
    const float* __restrict__ radius, const float* __restrict__ hth,
    const float* __restrict__ hph, const float* __restrict__ br,
    const float* __restrict__ W1, const float* __restrict__ b1,
    const float* __restrict__ b2, const float* __restrict__ W3,
    const _Float16* __restrict__ Bws, float* __restrict__ out, int n) {
  const int lane = threadIdx.x & 63;
  const int wave = threadIdx.x >> 6;
  const int tile = blockIdx.x * 4 + wave;
  const int quad = lane >> 4, col = lane & 15;
  const int pbase = tile * 16;
  if (pbase >= n) return;

  // ---- A-fragment generation: lane's point m=col, h = 32*ks + quad*8 + jj ----
  float p = phi[pbase + col], t = theta[pbase + col];
  half8 aYh[2], aYl[2], aF1h[2], aF1l[2], aF2[2], aF3[2];
#pragma unroll
  for (int ks = 0; ks < 2; ++ks) {
#pragma unroll
    for (int jj = 0; jj < 8; ++jj) {
      int h = ks * 32 + quad * 8 + jj;
      float z = fmaf(p, W1[h], fmaf(t, W1[NH + h], b1[h]));
      float y = fast_tanh(z);
      float f1 = fmaf(-y, y, 1.0f);
      float f2a = y * f1;                       // true f2 = -2*y*f1; -2 folded into B
      float f3 = f1 * fmaf(-6.0f, f1, 4.0f);
      _Float16 yh = (_Float16)y;
      _Float16 f1h = (_Float16)f1;
      aYh[ks][jj] = yh;   aYl[ks][jj] = (_Float16)(y - (float)yh);
      aF1h[ks][jj] = f1h; aF1l[ks][jj] = (_Float16)(f1 - (float)f1h);
      aF2[ks][jj] = (_Float16)f2a;
      aF3[ks][jj] = (_Float16)f3;
    }
  }

  float4v Tacc[9];
#pragma unroll
  for (int x = 0; x < 9; ++x) Tacc[x] = (float4v){0.f, 0.f, 0.f, 0.f};

#pragma unroll
  for (int nt = 0; nt < 4; ++nt) {
    float4v acc[10];
#pragma unroll
    for (int k = 0; k < 10; ++k) acc[k] = (float4v){0.f, 0.f, 0.f, 0.f};
#pragma unroll
    for (int ks = 0; ks < 2; ++ks) {
#pragma unroll
      for (int k = 0; k < 10; ++k) {
        half8 ah = (k == 0) ? aYh[ks] : (k < 3) ? aF1h[ks] : (k < 6) ? aF2[ks] : aF3[ks];
        half8 bh = ldB(Bws, k, nt, ks, lane);
        acc[k] = __builtin_amdgcn_mfma_f32_16x16x32_f16(ah, bh, acc[k], 0, 0, 0);
        if (k < 3) {
          half8 al = (k == 0) ? aYl[ks] : aF1l[ks];
          acc[k] = __builtin_amdgcn_mfma_f32_16x16x32_f16(al, bh, acc[k], 0, 0, 0);
          half8 bl = ldB(Bws, 10 + k, nt, ks, lane);
          acc[k] = __builtin_amdgcn_mfma_f32_16x16x32_f16(ah, bl, acc[k], 0, 0, 0);
        }
      }
    }
    // ---- Faa di Bruno + W3 on C-layout: lane holds (point=quad*4+r, j=nt*16+col) ----
    float b2v = b2[nt * 16 + col];
    float w3v = W3[nt * 16 + col];
#pragma unroll
    for (int r = 0; r < 4; ++r) {
      float z0 = acc[0][r] + b2v;
      float y2 = fast_tanh(z0);
      float g1 = fmaf(-y2, y2, 1.0f);
      float g2 = -2.0f * (y2 * g1);
      float g3 = g1 * fmaf(-6.0f, g1, 4.0f);
      float gp = acc[1][r], gt = acc[2][r];
      float gpp = acc[3][r], gpt = acc[4][r], gtt = acc[5][r];
      float zppp = acc[6][r], zppt = acc[7][r], zptt = acc[8][r], zttt = acc[9][r];
      float gp2 = gp * gp, gt2 = gt * gt;
      Tacc[0][r] = fmaf(w3v, g1 * gp, Tacc[0][r]);
      Tacc[1][r] = fmaf(w3v, g1 * gt, Tacc[1][r]);
      Tacc[2][r] = fmaf(w3v, fmaf(g2, gp2, g1 * gpp), Tacc[2][r]);
      Tacc[3][r] = fmaf(w3v, fmaf(g2, gp * gt, g1 * gpt), Tacc[3][r]);
      Tacc[4][r] = fmaf(w3v, fmaf(g2, gt2, g1 * gtt), Tacc[4][r]);
      Tacc[5][r] = fmaf(w3v, fmaf(g3, gp2 * gp, fmaf(3.0f * g2, gp * gpp, g1 * zppp)), Tacc[5][r]);
      Tacc[6][r] = fmaf(w3v, fmaf(g3, gp2 * gt, fmaf(g2, fmaf(2.0f, gp * gpt, gt * gpp), g1 * zppt)), Tacc[6][r]);
      Tacc[7][r] = fmaf(w3v, fmaf(g3, gp * gt2, fmaf(g2, fmaf(2.0f, gt * gpt, gp * gtt), g1 * zptt)), Tacc[7][r]);
      Tacc[8][r] = fmaf(w3v, fmaf(g3, gt2 * gt, fmaf(3.0f * g2, gt * gtt, g1 * zttt)), Tacc[8][r]);
    }
  }

  // ---- reduce over j: butterfly across the 16 cols (same quad group) ----
#pragma unroll
  for (int x = 0; x < 9; ++x) {
#pragma unroll
    for (int r = 0; r < 4; ++r) {
      float v = Tacc[x][r];
      v += __shfl_xor(v, 1, 16);
      v += __shfl_xor(v, 2, 16);
      v += __shfl_xor(v, 4, 16);
      v += __shfl_xor(v, 8, 16);
      Tacc[x][r] = v;
    }
  }

  // lane handles point = quad*4 + (col&3); lanes col<4 store.
  int rsel = col & 3;
  float T[9];
#pragma unroll
  for (int x = 0; x < 9; ++x) {
    float4v v = Tacc[x];
    T[x] = (rsel == 0) ? v[0] : (rsel == 1) ? v[1] : (rsel == 2) ? v[2] : v[3];
  }
  float Tp = T[0], Tt = T[1], Tpp = T[2], Tpt = T[3], Ttt = T[4];
  float Tppp = T[5], Tppt = T[6], Tptt = T[7], Tttt = T[8];

  int pi = pbase + quad * 4 + rsel;
  float t2 = theta[pi];
  float s = sinf(t2), c = cosf(t2);
  float inv_s = 1.0f / s;
  float inv_s2 = inv_s * inv_s;

  float A = Tp * inv_s + Tt;          // u_theta
  float D = Tp * inv_s - Tt;          // u_phi
  float q1 = Tpt * inv_s - Tp * c * inv_s2;
  float A_t = q1 + Ttt;
  float D_t = q1 - Ttt;
  float q2 = Tptt * inv_s - 2.0f * Tpt * c * inv_s2
           + Tp * (s * s + 2.0f * c * c) * inv_s2 * inv_s;
  float A_tt = q2 + Tttt;
  float D_tt = q2 - Tttt;
  float A_pp = Tppp * inv_s + Tppt;
  float D_p  = Tpp * inv_s - Tpt;
  float D_pp = Tppp * inv_s - Tppt;

  float utt   = -(A_t * s + A * c);
  float uttt  = -(A_tt * s + 2.0f * A_t * c - A * s) * s + utt * c;
  float utpp  = -A_pp;
  float upht  = D_t * s + D * c;
  float uphtt = (D_tt * s + 2.0f * D_t * c - D * s) * s + upht * c;
  float upp   = D_p;
  float uppp  = D_pp;

  float r = radius[pi];
  float inv_r = 1.0f / r;
  float inv_r2 = inv_r * inv_r;
  float div_uh = (utt + upp) * inv_r * inv_s;
  float lap_t = s * inv_r2 * uttt + utpp * inv_s2 * inv_r2;
  float lap_p = s * inv_r2 * uphtt + uppp * inv_s2 * inv_r2;
  float comp = s * (lap_t * lap_t + lap_p * lap_p);
  float sv = -(A * hth[pi] + D * hph[pi]) - br[pi] * div_uh;
  float tg = div_uh - A * (s / c) * inv_r;

  if (col < 4) {
    out[pi]         = A;
    out[n + pi]     = D;
    out[2 * n + pi] = div_uh;
    out[3 * n + pi] = sv;
    out[4 * n + pi] = tg;
    out[5 * n + pi] = comp;
  }
}

extern "C" void kernel_launch(void* const* d_in, const int* in_sizes, int n_in,
                              void* d_out, int out_size, void* d_ws, size_t ws_size,
                              hipStream_t stream) {
  const float* phi    = (const float*)d_in[0];
  const float* theta  = (const float*)d_in[1];
  const float* radius = (const float*)d_in[2];
  const float* hth    = (const float*)d_in[3];
  const float* hph    = (const float*)d_in[4];
  const float* br     = (const float*)d_in[5];
  const float* W1     = (const float*)d_in[6];
  const float* b1     = (const float*)d_in[7];
  const float* W2     = (const float*)d_in[8];
  const float* b2     = (const float*)d_in[9];
  const float* W3     = (const float*)d_in[10];
  (void)ws_size; (void)n_in; (void)out_size;

  _Float16* Bws = (_Float16*)d_ws;     // 13 slots * 4 nt * 2 ks * 512 halfs = 104 KB
  float* out = (float*)d_out;
  int n = in_sizes[0];

  prep_B<<<(NH * NH + 255) / 256, 256, 0, stream>>>(W1, W2, Bws);
  int ntiles = (n + 15) / 16;
  int nblocks = (ntiles + 3) / 4;
  pinn_mfma<<<nblocks, 256, 0, stream>>>(
      phi, theta, radius, hth, hph, br, W1, b1, b2, W3, Bws, out, n);
}